// Round 2
// baseline (5966.041 us; speedup 1.0000x reference)
//
#include <hip/hip_runtime.h>
#include <math.h>

#define LOG2E 1.4426950408889634f

constexpr int B_ = 4, N_ = 2048, H_ = 4, D_ = 32, HD_ = 128;
constexpr int BH_ = B_ * H_;          // 16
constexpr int ROWS_ = BH_ * N_;       // 32768
constexpr size_t M_ = (size_t)ROWS_ * D_;  // 1,048,576 floats

typedef float v2f __attribute__((ext_vector_type(2)));
typedef float v4f __attribute__((ext_vector_type(4)));

// x[BN,K] @ Wl/Wr[K,128] + bl/br -> xl,xr stored as [B,H,N,D]
__global__ __launch_bounds__(256) void k_linear(
    const float* __restrict__ x,
    const float* __restrict__ Wl, const float* __restrict__ bl,
    const float* __restrict__ Wr, const float* __restrict__ br,
    float* __restrict__ xl, float* __restrict__ xr, int K)
{
    __shared__ __align__(16) float xs[32 * 128];
    const int tid = threadIdx.x;
    const int r0 = blockIdx.x * 32;
    const float4* src = (const float4*)(x + (size_t)r0 * K);
    float4* dst = (float4*)xs;
    for (int idx = tid; idx < 8 * K; idx += 256) dst[idx] = src[idx];
    __syncthreads();

    const int c  = tid & 127;
    const int rg = tid >> 7;
    float accl[16], accr[16];
    const float blv = bl[c], brv = br[c];
    #pragma unroll
    for (int r = 0; r < 16; r++) { accl[r] = blv; accr[r] = brv; }
    #pragma unroll 8
    for (int k = 0; k < K; k++) {
        const float wl = Wl[k * HD_ + c];
        const float wr = Wr[k * HD_ + c];
        #pragma unroll
        for (int r = 0; r < 16; r++) {
            const float xv = xs[(rg * 16 + r) * K + k];
            accl[r] = fmaf(xv, wl, accl[r]);
            accr[r] = fmaf(xv, wr, accr[r]);
        }
    }
    const int h = c >> 5, d = c & 31;
    #pragma unroll
    for (int r = 0; r < 16; r++) {
        const int row = r0 + rg * 16 + r;
        const int b = row >> 11, n = row & (N_ - 1);
        const size_t o = (((size_t)(b * H_ + h)) * N_ + n) * D_ + d;
        xl[o] = accl[r];
        xr[o] = accr[r];
    }
}

// u_j = 0.6*log2e * att_h . xl_j   (source-side rank-1 part; target-side v_i
// cancels in softmax over j -> dropped entirely)
__global__ __launch_bounds__(256) void k_u(
    const float* __restrict__ xl, const float* __restrict__ att,
    float* __restrict__ u)
{
    const int idx = blockIdx.x * 256 + threadIdx.x; // [0, ROWS_)
    const int h = (idx / N_) & (H_ - 1);
    const float4* a4 = (const float4*)(att + h * D_);
    const float4* l4 = (const float4*)(xl + (size_t)idx * D_);
    float su = 0.f;
    #pragma unroll
    for (int q = 0; q < 8; q++) {
        const float4 a = a4[q], lv = l4[q];
        su += a.x * lv.x + a.y * lv.y + a.z * lv.z + a.w * lv.w;
    }
    u[idx] = 0.6f * LOG2E * su;
}

// Flash-style GATv2 attention, j-split across `part` blocks.
// Lane pair shares one target row i (d split 16+16).
// e_ij (log2 domain, shifted) = u_j + sum_d tc_d * |xl_jd + xr_id|
// Writes UNNORMALIZED o plus (m,l) per row for the combine pass.
__global__ __launch_bounds__(128, 4) void k_attn(
    const float* __restrict__ xl, const float* __restrict__ xr,
    const float* __restrict__ u, const float* __restrict__ att,
    float* __restrict__ P, float* __restrict__ mb, float* __restrict__ lb,
    int jlen)
{
    __shared__ __align__(16) float xs[64 * D_];
    __shared__ float us[64];
    const int tid = threadIdx.x;
    const int r = tid >> 1, dh = tid & 1;
    const int tile = blockIdx.x & 511;
    const int part = blockIdx.x >> 9;
    const int bh = tile >> 5;
    const int i  = (tile & 31) * 64 + r;
    const int h  = bh & (H_ - 1);
    const int row = bh * N_ + i;
    const size_t rowbase = (size_t)row * D_ + dh * 16;

    v2f xr2[8], tc2[8];
    {
        const v4f* xv4 = (const v4f*)(xr + rowbase);
        const v4f* av4 = (const v4f*)(att + h * D_ + dh * 16);
        #pragma unroll
        for (int q = 0; q < 4; q++) {
            v4f xv = xv4[q];
            v4f av = av4[q] * (0.4f * LOG2E);
            xr2[2*q]   = xv.xy; xr2[2*q+1] = xv.zw;
            tc2[2*q]   = av.xy; tc2[2*q+1] = av.zw;
        }
    }

    float m = -INFINITY, l = 0.f;
    v2f o2[8];
    #pragma unroll
    for (int k = 0; k < 8; k++) o2[k] = (v2f){0.f, 0.f};

    const int jbeg = part * jlen, jend = jbeg + jlen;
    for (int j0 = jbeg; j0 < jend; j0 += 64) {
        const float4* src = (const float4*)(xl + ((size_t)bh * N_ + j0) * D_);
        #pragma unroll
        for (int it = 0; it < 4; it++)
            ((float4*)xs)[tid + 128 * it] = src[tid + 128 * it];
        if (tid < 64) us[tid] = u[bh * N_ + j0 + tid];
        __syncthreads();

        #pragma unroll 1
        for (int jj = 0; jj < 64; jj += 16) {
            float e16[16];
            #pragma unroll
            for (int q = 0; q < 16; q++) {
                const v4f* row4 = (const v4f*)(xs + (jj + q) * D_ + dh * 16);
                v2f a0 = (v2f){0.f, 0.f}, a1 = (v2f){0.f, 0.f};
                #pragma unroll
                for (int k = 0; k < 4; k++) {
                    const v4f t = row4[k];
                    v2f z0 = t.xy + xr2[2*k];
                    v2f z1 = t.zw + xr2[2*k+1];
                    z0 = __builtin_elementwise_max(z0, -z0);   // v_pk_max neg-mod = |z|
                    z1 = __builtin_elementwise_max(z1, -z1);
                    a0 += tc2[2*k]   * z0;                     // v_pk_fma
                    a1 += tc2[2*k+1] * z1;
                }
                const v2f a = a0 + a1;
                float prt = a.x + a.y;
                prt += __shfl_xor(prt, 1);
                e16[q] = prt + us[jj + q];
            }
            // tile max (tree)
            float t0 = fmaxf(fmaxf(fmaxf(e16[0], e16[1]), fmaxf(e16[2], e16[3])),
                             fmaxf(fmaxf(e16[4], e16[5]), fmaxf(e16[6], e16[7])));
            float t1 = fmaxf(fmaxf(fmaxf(e16[8], e16[9]), fmaxf(e16[10], e16[11])),
                             fmaxf(fmaxf(e16[12], e16[13]), fmaxf(e16[14], e16[15])));
            const float mn = fmaxf(m, fmaxf(t0, t1));
            const float al = exp2f(m - mn);
            m = mn;
            l *= al;
            const v2f alv = (v2f){al, al};
            #pragma unroll
            for (int k = 0; k < 8; k++) o2[k] *= alv;
            #pragma unroll
            for (int q = 0; q < 16; q++) {
                const float p = exp2f(e16[q] - m);
                l += p;
                const v4f* row4 = (const v4f*)(xs + (jj + q) * D_ + dh * 16);
                const v2f pv = (v2f){p, p};
                #pragma unroll
                for (int k = 0; k < 4; k++) {
                    const v4f t = row4[k];
                    o2[2*k]   += pv * t.xy;
                    o2[2*k+1] += pv * t.zw;
                }
            }
        }
        __syncthreads();
    }

    float* Pp = P + (size_t)part * M_;
    #pragma unroll
    for (int q = 0; q < 4; q++) {
        v4f w;
        w.xy = o2[2*q]; w.zw = o2[2*q+1];
        *(v4f*)(Pp + rowbase + q * 4) = w;
    }
    if (dh == 0) {
        mb[part * ROWS_ + row] = m;
        lb[part * ROWS_ + row] = l;
    }
}

// merge JS partial (o,m,l) -> normalized attention output
template <int JS>
__global__ __launch_bounds__(256) void k_combine(
    const float* __restrict__ P, const float* __restrict__ mb,
    const float* __restrict__ lb, float* __restrict__ ao)
{
    const int idx = blockIdx.x * 256 + threadIdx.x;  // [0, ROWS_*D_)
    const int row = idx >> 5;
    float mv[JS], lv[JS];
    #pragma unroll
    for (int s = 0; s < JS; s++) { mv[s] = mb[s * ROWS_ + row]; lv[s] = lb[s * ROWS_ + row]; }
    float M = mv[0];
    #pragma unroll
    for (int s = 1; s < JS; s++) M = fmaxf(M, mv[s]);
    float w[JS], L = 0.f;
    #pragma unroll
    for (int s = 0; s < JS; s++) { w[s] = exp2f(mv[s] - M); L += w[s] * lv[s]; }
    const float inv = 1.f / L;
    float acc = 0.f;
    #pragma unroll
    for (int s = 0; s < JS; s++) acc += w[s] * P[(size_t)s * M_ + idx];
    ao[idx] = acc * inv;
}

// bias add + LayerNorm(128) (+optional ReLU); input [B,H,N,32] -> [B,N,128]
__global__ __launch_bounds__(64) void k_ln(
    const float* __restrict__ ain, const float* __restrict__ bias,
    const float* __restrict__ g, const float* __restrict__ bta,
    float* __restrict__ outp, int do_relu)
{
    const int row = blockIdx.x;
    const int b = row >> 11, n = row & (N_ - 1);
    const int t = threadIdx.x;
    const int c0 = t, c1 = t + 64;
    const size_t i0 = (((size_t)(b * H_ + (c0 >> 5))) * N_ + n) * D_ + (c0 & 31);
    const size_t i1 = (((size_t)(b * H_ + (c1 >> 5))) * N_ + n) * D_ + (c1 & 31);
    const float x0 = ain[i0] + bias[c0];
    const float x1 = ain[i1] + bias[c1];
    float s = x0 + x1;
    #pragma unroll
    for (int w = 1; w < 64; w <<= 1) s += __shfl_xor(s, w);
    const float mu = s * (1.f / 128.f);
    const float d0 = x0 - mu, d1 = x1 - mu;
    float q = d0 * d0 + d1 * d1;
    #pragma unroll
    for (int w = 1; w < 64; w <<= 1) q += __shfl_xor(q, w);
    const float rstd = rsqrtf(q * (1.f / 128.f) + 1e-5f);
    float y0 = d0 * rstd * g[c0] + bta[c0];
    float y1 = d1 * rstd * g[c1] + bta[c1];
    if (do_relu) { y0 = fmaxf(y0, 0.f); y1 = fmaxf(y1, 0.f); }
    outp[(size_t)row * HD_ + c0] = y0;
    outp[(size_t)row * HD_ + c1] = y1;
}

extern "C" void kernel_launch(void* const* d_in, const int* in_sizes, int n_in,
                              void* d_out, int out_size, void* d_ws, size_t ws_size,
                              hipStream_t stream) {
    const float* x    = (const float*)d_in[0];
    const float* Wl1  = (const float*)d_in[2];
    const float* bl1  = (const float*)d_in[3];
    const float* Wr1  = (const float*)d_in[4];
    const float* br1  = (const float*)d_in[5];
    const float* att1 = (const float*)d_in[6];
    const float* bias1= (const float*)d_in[7];
    const float* ln1g = (const float*)d_in[8];
    const float* ln1b = (const float*)d_in[9];
    const float* Wl2  = (const float*)d_in[10];
    const float* bl2  = (const float*)d_in[11];
    const float* Wr2  = (const float*)d_in[12];
    const float* br2  = (const float*)d_in[13];
    const float* att2 = (const float*)d_in[14];
    const float* bias2= (const float*)d_in[15];
    const float* ln2g = (const float*)d_in[16];
    const float* ln2b = (const float*)d_in[17];

    float* ws = (float*)d_ws;
    float* xl = ws;                       // M_  (also reused as combine output "ao")
    float* xr = xl + M_;                  // M_
    float* u  = xr + M_;                  // ROWS_

    // j-split factor: 4 if workspace allows, else 1 (round-1 footprint)
    const size_t need4 = (2 * M_ + ROWS_ + 4 * M_ + 8 * (size_t)ROWS_) * sizeof(float);
    const int js = (ws_size >= need4) ? 4 : 1;
    const int jlen = N_ / js;

    float* P  = u + ROWS_;                // js * M_
    float* mb = P + (size_t)js * M_;      // js * ROWS_
    float* lb = mb + (size_t)js * ROWS_;  // js * ROWS_
    float* h  = (js == 4) ? (P + M_) : (lb + (size_t)js * ROWS_);  // M_ (aliases P1 when js=4)
    float* ao = xl;                       // combine output aliases xl (dead after attn)
    float* outf = (float*)d_out;

    const int BN = B_ * N_;               // 8192
    // ---- layer 1 ----
    k_linear<<<BN / 32, 256, 0, stream>>>(x, Wl1, bl1, Wr1, br1, xl, xr, 32);
    k_u<<<ROWS_ / 256, 256, 0, stream>>>(xl, att1, u);
    k_attn<<<512 * js, 128, 0, stream>>>(xl, xr, u, att1, P, mb, lb, jlen);
    if (js == 4) k_combine<4><<<(ROWS_ * D_) / 256, 256, 0, stream>>>(P, mb, lb, ao);
    else         k_combine<1><<<(ROWS_ * D_) / 256, 256, 0, stream>>>(P, mb, lb, ao);
    k_ln<<<BN, 64, 0, stream>>>(ao, bias1, ln1g, ln1b, h, 1);
    // ---- layer 2 ----
    k_linear<<<BN / 32, 256, 0, stream>>>(h, Wl2, bl2, Wr2, br2, xl, xr, 128);
    k_u<<<ROWS_ / 256, 256, 0, stream>>>(xl, att2, u);
    k_attn<<<512 * js, 128, 0, stream>>>(xl, xr, u, att2, P, mb, lb, jlen);
    if (js == 4) k_combine<4><<<(ROWS_ * D_) / 256, 256, 0, stream>>>(P, mb, lb, ao);
    else         k_combine<1><<<(ROWS_ * D_) / 256, 256, 0, stream>>>(P, mb, lb, ao);
    k_ln<<<BN, 64, 0, stream>>>(ao, bias2, ln2g, ln2b, outf, 0);
}

// Round 3
// 5890.090 us; speedup vs baseline: 1.0129x; 1.0129x over previous
//
#include <hip/hip_runtime.h>
#include <math.h>

#define LOG2E 1.4426950408889634f

constexpr int B_ = 4, N_ = 2048, H_ = 4, D_ = 32, HD_ = 128;
constexpr int BH_ = B_ * H_;          // 16
constexpr int ROWS_ = BH_ * N_;       // 32768
constexpr size_t M_ = (size_t)ROWS_ * D_;  // 1,048,576 floats

typedef float v2f __attribute__((ext_vector_type(2)));
typedef float v4f __attribute__((ext_vector_type(4)));

// x[BN,K] @ Wl/Wr[K,128] + bl/br -> xl,xr stored as [B,H,N,D]
__global__ __launch_bounds__(256) void k_linear(
    const float* __restrict__ x,
    const float* __restrict__ Wl, const float* __restrict__ bl,
    const float* __restrict__ Wr, const float* __restrict__ br,
    float* __restrict__ xl, float* __restrict__ xr, int K)
{
    __shared__ __align__(16) float xs[32 * 128];
    const int tid = threadIdx.x;
    const int r0 = blockIdx.x * 32;
    const float4* src = (const float4*)(x + (size_t)r0 * K);
    float4* dst = (float4*)xs;
    for (int idx = tid; idx < 8 * K; idx += 256) dst[idx] = src[idx];
    __syncthreads();

    const int c  = tid & 127;
    const int rg = tid >> 7;
    float accl[16], accr[16];
    const float blv = bl[c], brv = br[c];
    #pragma unroll
    for (int r = 0; r < 16; r++) { accl[r] = blv; accr[r] = brv; }
    #pragma unroll 8
    for (int k = 0; k < K; k++) {
        const float wl = Wl[k * HD_ + c];
        const float wr = Wr[k * HD_ + c];
        #pragma unroll
        for (int r = 0; r < 16; r++) {
            const float xv = xs[(rg * 16 + r) * K + k];
            accl[r] = fmaf(xv, wl, accl[r]);
            accr[r] = fmaf(xv, wr, accr[r]);
        }
    }
    const int h = c >> 5, d = c & 31;
    #pragma unroll
    for (int r = 0; r < 16; r++) {
        const int row = r0 + rg * 16 + r;
        const int b = row >> 11, n = row & (N_ - 1);
        const size_t o = (((size_t)(b * H_ + h)) * N_ + n) * D_ + d;
        xl[o] = accl[r];
        xr[o] = accr[r];
    }
}

// u_j = 0.6*log2e * att_h . xl_j   (source-side rank-1 part; target-side v_i
// cancels in softmax over j -> dropped entirely)
__global__ __launch_bounds__(256) void k_u(
    const float* __restrict__ xl, const float* __restrict__ att,
    float* __restrict__ u)
{
    const int idx = blockIdx.x * 256 + threadIdx.x; // [0, ROWS_)
    const int h = (idx / N_) & (H_ - 1);
    const float4* a4 = (const float4*)(att + h * D_);
    const float4* l4 = (const float4*)(xl + (size_t)idx * D_);
    float su = 0.f;
    #pragma unroll
    for (int q = 0; q < 8; q++) {
        const float4 a = a4[q], lv = l4[q];
        su += a.x * lv.x + a.y * lv.y + a.z * lv.z + a.w * lv.w;
    }
    u[idx] = 0.6f * LOG2E * su;
}

// Flash-style GATv2 attention, j-split across `part` blocks.
// Lane pair shares one target row i (d split 16+16).
// e_ij (log2 domain, shifted) = u_j + sum_d tc_d * |xl_jd + xr_id|
// Writes UNNORMALIZED o plus (m,l) per row for the combine pass.
// waves_per_eu(4,4): pin VGPR budget to 128 (min=max so the allocator
// neither spills to chase 8 waves nor balloons past 128).
__global__ __attribute__((amdgpu_waves_per_eu(4, 4))) __launch_bounds__(128)
void k_attn(
    const float* __restrict__ xl, const float* __restrict__ xr,
    const float* __restrict__ u, const float* __restrict__ att,
    float* __restrict__ P, float* __restrict__ mb, float* __restrict__ lb,
    int jlen)
{
    __shared__ __align__(16) float xs[64 * D_];
    __shared__ float us[64];
    const int tid = threadIdx.x;
    const int r = tid >> 1, dh = tid & 1;
    const int tile = blockIdx.x & 511;
    const int part = blockIdx.x >> 9;
    const int bh = tile >> 5;
    const int i  = (tile & 31) * 64 + r;
    const int h  = bh & (H_ - 1);
    const int row = bh * N_ + i;
    const size_t rowbase = (size_t)row * D_ + dh * 16;

    v2f xr2[8], tc2[8];
    {
        const v4f* xv4 = (const v4f*)(xr + rowbase);
        const v4f* av4 = (const v4f*)(att + h * D_ + dh * 16);
        #pragma unroll
        for (int q = 0; q < 4; q++) {
            v4f xv = xv4[q];
            v4f av = av4[q] * (0.4f * LOG2E);
            xr2[2*q]   = xv.xy; xr2[2*q+1] = xv.zw;
            tc2[2*q]   = av.xy; tc2[2*q+1] = av.zw;
        }
    }

    float m = -INFINITY, l = 0.f;
    v2f o2[8];
    #pragma unroll
    for (int k = 0; k < 8; k++) o2[k] = (v2f){0.f, 0.f};

    const int jbeg = part * jlen, jend = jbeg + jlen;
    for (int j0 = jbeg; j0 < jend; j0 += 64) {
        const float4* src = (const float4*)(xl + ((size_t)bh * N_ + j0) * D_);
        #pragma unroll
        for (int it = 0; it < 4; it++)
            ((float4*)xs)[tid + 128 * it] = src[tid + 128 * it];
        if (tid < 64) us[tid] = u[bh * N_ + j0 + tid];
        __syncthreads();

        #pragma unroll 1
        for (int jj = 0; jj < 64; jj += 16) {
            float e16[16];
            #pragma unroll
            for (int q = 0; q < 16; q++) {
                const v4f* row4 = (const v4f*)(xs + (jj + q) * D_ + dh * 16);
                v2f a0 = (v2f){0.f, 0.f}, a1 = (v2f){0.f, 0.f};
                #pragma unroll
                for (int k = 0; k < 4; k++) {
                    const v4f t = row4[k];
                    v2f z0 = t.xy + xr2[2*k];
                    v2f z1 = t.zw + xr2[2*k+1];
                    z0 = __builtin_elementwise_max(z0, -z0);   // v_pk_max neg-mod = |z|
                    z1 = __builtin_elementwise_max(z1, -z1);
                    a0 += tc2[2*k]   * z0;                     // v_pk_fma
                    a1 += tc2[2*k+1] * z1;
                }
                const v2f a = a0 + a1;
                float prt = a.x + a.y;
                prt += __shfl_xor(prt, 1);
                e16[q] = prt + us[jj + q];
            }
            // tile max (tree)
            float t0 = fmaxf(fmaxf(fmaxf(e16[0], e16[1]), fmaxf(e16[2], e16[3])),
                             fmaxf(fmaxf(e16[4], e16[5]), fmaxf(e16[6], e16[7])));
            float t1 = fmaxf(fmaxf(fmaxf(e16[8], e16[9]), fmaxf(e16[10], e16[11])),
                             fmaxf(fmaxf(e16[12], e16[13]), fmaxf(e16[14], e16[15])));
            const float mn = fmaxf(m, fmaxf(t0, t1));
            const float al = exp2f(m - mn);
            m = mn;
            l *= al;
            const v2f alv = (v2f){al, al};
            #pragma unroll
            for (int k = 0; k < 8; k++) o2[k] *= alv;
            #pragma unroll
            for (int q = 0; q < 16; q++) {
                const float p = exp2f(e16[q] - m);
                l += p;
                const v4f* row4 = (const v4f*)(xs + (jj + q) * D_ + dh * 16);
                const v2f pv = (v2f){p, p};
                #pragma unroll
                for (int k = 0; k < 4; k++) {
                    const v4f t = row4[k];
                    o2[2*k]   += pv * t.xy;
                    o2[2*k+1] += pv * t.zw;
                }
            }
        }
        __syncthreads();
    }

    float* Pp = P + (size_t)part * M_;
    #pragma unroll
    for (int q = 0; q < 4; q++) {
        v4f w;
        w.xy = o2[2*q]; w.zw = o2[2*q+1];
        *(v4f*)(Pp + rowbase + q * 4) = w;
    }
    if (dh == 0) {
        mb[part * ROWS_ + row] = m;
        lb[part * ROWS_ + row] = l;
    }
}

// merge JS partial (o,m,l) -> normalized attention output
template <int JS>
__global__ __launch_bounds__(256) void k_combine(
    const float* __restrict__ P, const float* __restrict__ mb,
    const float* __restrict__ lb, float* __restrict__ ao)
{
    const int idx = blockIdx.x * 256 + threadIdx.x;  // [0, ROWS_*D_)
    const int row = idx >> 5;
    float mv[JS], lv[JS];
    #pragma unroll
    for (int s = 0; s < JS; s++) { mv[s] = mb[s * ROWS_ + row]; lv[s] = lb[s * ROWS_ + row]; }
    float M = mv[0];
    #pragma unroll
    for (int s = 1; s < JS; s++) M = fmaxf(M, mv[s]);
    float w[JS], L = 0.f;
    #pragma unroll
    for (int s = 0; s < JS; s++) { w[s] = exp2f(mv[s] - M); L += w[s] * lv[s]; }
    const float inv = 1.f / L;
    float acc = 0.f;
    #pragma unroll
    for (int s = 0; s < JS; s++) acc += w[s] * P[(size_t)s * M_ + idx];
    ao[idx] = acc * inv;
}

// bias add + LayerNorm(128) (+optional ReLU); input [B,H,N,32] -> [B,N,128]
__global__ __launch_bounds__(64) void k_ln(
    const float* __restrict__ ain, const float* __restrict__ bias,
    const float* __restrict__ g, const float* __restrict__ bta,
    float* __restrict__ outp, int do_relu)
{
    const int row = blockIdx.x;
    const int b = row >> 11, n = row & (N_ - 1);
    const int t = threadIdx.x;
    const int c0 = t, c1 = t + 64;
    const size_t i0 = (((size_t)(b * H_ + (c0 >> 5))) * N_ + n) * D_ + (c0 & 31);
    const size_t i1 = (((size_t)(b * H_ + (c1 >> 5))) * N_ + n) * D_ + (c1 & 31);
    const float x0 = ain[i0] + bias[c0];
    const float x1 = ain[i1] + bias[c1];
    float s = x0 + x1;
    #pragma unroll
    for (int w = 1; w < 64; w <<= 1) s += __shfl_xor(s, w);
    const float mu = s * (1.f / 128.f);
    const float d0 = x0 - mu, d1 = x1 - mu;
    float q = d0 * d0 + d1 * d1;
    #pragma unroll
    for (int w = 1; w < 64; w <<= 1) q += __shfl_xor(q, w);
    const float rstd = rsqrtf(q * (1.f / 128.f) + 1e-5f);
    float y0 = d0 * rstd * g[c0] + bta[c0];
    float y1 = d1 * rstd * g[c1] + bta[c1];
    if (do_relu) { y0 = fmaxf(y0, 0.f); y1 = fmaxf(y1, 0.f); }
    outp[(size_t)row * HD_ + c0] = y0;
    outp[(size_t)row * HD_ + c1] = y1;
}

extern "C" void kernel_launch(void* const* d_in, const int* in_sizes, int n_in,
                              void* d_out, int out_size, void* d_ws, size_t ws_size,
                              hipStream_t stream) {
    const float* x    = (const float*)d_in[0];
    const float* Wl1  = (const float*)d_in[2];
    const float* bl1  = (const float*)d_in[3];
    const float* Wr1  = (const float*)d_in[4];
    const float* br1  = (const float*)d_in[5];
    const float* att1 = (const float*)d_in[6];
    const float* bias1= (const float*)d_in[7];
    const float* ln1g = (const float*)d_in[8];
    const float* ln1b = (const float*)d_in[9];
    const float* Wl2  = (const float*)d_in[10];
    const float* bl2  = (const float*)d_in[11];
    const float* Wr2  = (const float*)d_in[12];
    const float* br2  = (const float*)d_in[13];
    const float* att2 = (const float*)d_in[14];
    const float* bias2= (const float*)d_in[15];
    const float* ln2g = (const float*)d_in[16];
    const float* ln2b = (const float*)d_in[17];

    float* ws = (float*)d_ws;
    float* xl = ws;                       // M_  (also reused as combine output "ao")
    float* xr = xl + M_;                  // M_
    float* u  = xr + M_;                  // ROWS_

    // j-split factor: 4 if workspace allows, else 1 (round-1 footprint)
    const size_t need4 = (2 * M_ + ROWS_ + 4 * M_ + 8 * (size_t)ROWS_) * sizeof(float);
    const int js = (ws_size >= need4) ? 4 : 1;
    const int jlen = N_ / js;

    float* P  = u + ROWS_;                // js * M_
    float* mb = P + (size_t)js * M_;      // js * ROWS_
    float* lb = mb + (size_t)js * ROWS_;  // js * ROWS_
    float* h  = (js == 4) ? (P + M_) : (lb + (size_t)js * ROWS_);  // M_ (aliases P1 when js=4)
    float* ao = xl;                       // combine output aliases xl (dead after attn)
    float* outf = (float*)d_out;

    const int BN = B_ * N_;               // 8192
    // ---- layer 1 ----
    k_linear<<<BN / 32, 256, 0, stream>>>(x, Wl1, bl1, Wr1, br1, xl, xr, 32);
    k_u<<<ROWS_ / 256, 256, 0, stream>>>(xl, att1, u);
    k_attn<<<512 * js, 128, 0, stream>>>(xl, xr, u, att1, P, mb, lb, jlen);
    if (js == 4) k_combine<4><<<(ROWS_ * D_) / 256, 256, 0, stream>>>(P, mb, lb, ao);
    else         k_combine<1><<<(ROWS_ * D_) / 256, 256, 0, stream>>>(P, mb, lb, ao);
    k_ln<<<BN, 64, 0, stream>>>(ao, bias1, ln1g, ln1b, h, 1);
    // ---- layer 2 ----
    k_linear<<<BN / 32, 256, 0, stream>>>(h, Wl2, bl2, Wr2, br2, xl, xr, 128);
    k_u<<<ROWS_ / 256, 256, 0, stream>>>(xl, att2, u);
    k_attn<<<512 * js, 128, 0, stream>>>(xl, xr, u, att2, P, mb, lb, jlen);
    if (js == 4) k_combine<4><<<(ROWS_ * D_) / 256, 256, 0, stream>>>(P, mb, lb, ao);
    else         k_combine<1><<<(ROWS_ * D_) / 256, 256, 0, stream>>>(P, mb, lb, ao);
    k_ln<<<BN, 64, 0, stream>>>(ao, bias2, ln2g, ln2b, outf, 0);
}

// Round 4
// 633.510 us; speedup vs baseline: 9.4174x; 9.2975x over previous
//
#include <hip/hip_runtime.h>
#include <math.h>

#define LOG2E 1.4426950408889634f

constexpr int B_ = 4, N_ = 2048, H_ = 4, D_ = 32, HD_ = 128;
constexpr int BH_ = B_ * H_;          // 16
constexpr int ROWS_ = BH_ * N_;       // 32768
constexpr size_t M_ = (size_t)ROWS_ * D_;  // 1,048,576 floats

typedef float v2f __attribute__((ext_vector_type(2)));
typedef float v4f __attribute__((ext_vector_type(4)));

static __device__ __forceinline__ v2f pabs2(v2f z) {
    return __builtin_elementwise_max(z, -z);   // v_pk_max with neg modifier
}

// x[BN,K] @ Wl/Wr[K,128] + bl/br -> xl,xr stored as [B,H,N,D]
__global__ __launch_bounds__(256) void k_linear(
    const float* __restrict__ x,
    const float* __restrict__ Wl, const float* __restrict__ bl,
    const float* __restrict__ Wr, const float* __restrict__ br,
    float* __restrict__ xl, float* __restrict__ xr, int K)
{
    __shared__ __align__(16) float xs[32 * 128];
    const int tid = threadIdx.x;
    const int r0 = blockIdx.x * 32;
    const float4* src = (const float4*)(x + (size_t)r0 * K);
    float4* dst = (float4*)xs;
    for (int idx = tid; idx < 8 * K; idx += 256) dst[idx] = src[idx];
    __syncthreads();

    const int c  = tid & 127;
    const int rg = tid >> 7;
    float accl[16], accr[16];
    const float blv = bl[c], brv = br[c];
    #pragma unroll
    for (int r = 0; r < 16; r++) { accl[r] = blv; accr[r] = brv; }
    #pragma unroll 8
    for (int k = 0; k < K; k++) {
        const float wl = Wl[k * HD_ + c];
        const float wr = Wr[k * HD_ + c];
        #pragma unroll
        for (int r = 0; r < 16; r++) {
            const float xv = xs[(rg * 16 + r) * K + k];
            accl[r] = fmaf(xv, wl, accl[r]);
            accr[r] = fmaf(xv, wr, accr[r]);
        }
    }
    const int h = c >> 5, d = c & 31;
    #pragma unroll
    for (int r = 0; r < 16; r++) {
        const int row = r0 + rg * 16 + r;
        const int b = row >> 11, n = row & (N_ - 1);
        const size_t o = (((size_t)(b * H_ + h)) * N_ + n) * D_ + d;
        xl[o] = accl[r];
        xr[o] = accr[r];
    }
}

// u_j = 0.6*log2e * att_h . xl_j   (source-side rank-1 part; target-side v_i
// cancels in softmax over j -> dropped entirely)
__global__ __launch_bounds__(256) void k_u(
    const float* __restrict__ xl, const float* __restrict__ att,
    float* __restrict__ u)
{
    const int idx = blockIdx.x * 256 + threadIdx.x; // [0, ROWS_)
    const int h = (idx / N_) & (H_ - 1);
    const float4* a4 = (const float4*)(att + h * D_);
    const float4* l4 = (const float4*)(xl + (size_t)idx * D_);
    float su = 0.f;
    #pragma unroll
    for (int q = 0; q < 8; q++) {
        const float4 a = a4[q], lv = l4[q];
        su += a.x * lv.x + a.y * lv.y + a.z * lv.z + a.w * lv.w;
    }
    u[idx] = 0.6f * LOG2E * su;
}

// Flash-style GATv2 attention, j-split across `part` blocks.
// Lane pair shares one target row i (d split 16+16, merged via shfl_xor(1)).
// e_ij (log2 domain, i-terms dropped) = u_j + sum_d tc_d * |xl_jd + xr_id|
// Online softmax with per-j running max; score regs feed PV directly
// (single set of LDS reads per j). NO occupancy attributes: measured twice
// that min-waves>=4 hints make the allocator squeeze to 64 VGPR and spill
// ~11 GB to scratch. Plain bounds gave VGPR=256, zero spill.
__global__ __launch_bounds__(128) void k_attn(
    const float* __restrict__ xl, const float* __restrict__ xr,
    const float* __restrict__ u, const float* __restrict__ att,
    float* __restrict__ P, float* __restrict__ mb, float* __restrict__ lb,
    int jlen)
{
    __shared__ __align__(16) float xs[64 * D_];
    __shared__ float us[64];
    const int tid = threadIdx.x;
    const int r = tid >> 1, dh = tid & 1;
    const int tile = blockIdx.x & 511;
    const int part = blockIdx.x >> 9;
    const int bh = tile >> 5;
    const int i  = (tile & 31) * 64 + r;
    const int h  = bh & (H_ - 1);
    const int row = bh * N_ + i;
    const size_t rowbase = (size_t)row * D_ + dh * 16;

    v2f xr2[8], tc2[8];
    {
        const v4f* xv4 = (const v4f*)(xr + rowbase);
        const v4f* av4 = (const v4f*)(att + h * D_ + dh * 16);
        #pragma unroll
        for (int q = 0; q < 4; q++) {
            v4f xv = xv4[q];
            v4f av = av4[q] * (0.4f * LOG2E);
            xr2[2*q]   = xv.xy; xr2[2*q+1] = xv.zw;
            tc2[2*q]   = av.xy; tc2[2*q+1] = av.zw;
        }
    }

    float m = -INFINITY, l = 0.f;
    v2f o2[8];
    #pragma unroll
    for (int k = 0; k < 8; k++) o2[k] = (v2f){0.f, 0.f};

    const int jbeg = part * jlen, jend = jbeg + jlen;
    for (int j0 = jbeg; j0 < jend; j0 += 64) {
        const float4* src = (const float4*)(xl + ((size_t)bh * N_ + j0) * D_);
        #pragma unroll
        for (int it = 0; it < 4; it++)
            ((float4*)xs)[tid + 128 * it] = src[tid + 128 * it];
        if (tid < 64) us[tid] = u[bh * N_ + j0 + tid];
        __syncthreads();

        #pragma unroll 2
        for (int q = 0; q < 64; q++) {
            const v4f* row4 = (const v4f*)(xs + q * D_ + dh * 16);
            const v4f t0 = row4[0], t1 = row4[1], t2 = row4[2], t3 = row4[3];
            v2f a0 = tc2[0] * pabs2(t0.xy + xr2[0]);
            v2f a1 = tc2[1] * pabs2(t0.zw + xr2[1]);
            a0 += tc2[2] * pabs2(t1.xy + xr2[2]);
            a1 += tc2[3] * pabs2(t1.zw + xr2[3]);
            a0 += tc2[4] * pabs2(t2.xy + xr2[4]);
            a1 += tc2[5] * pabs2(t2.zw + xr2[5]);
            a0 += tc2[6] * pabs2(t3.xy + xr2[6]);
            a1 += tc2[7] * pabs2(t3.zw + xr2[7]);
            const v2f a = a0 + a1;
            float prt = a.x + a.y;
            prt += __shfl_xor(prt, 1);
            const float e = prt + us[q];
            if (__builtin_expect(e > m, 0)) {      // rare after first tiles
                const float al = exp2f(m - e);
                m = e;
                l *= al;
                const v2f alv = (v2f){al, al};
                #pragma unroll
                for (int k = 0; k < 8; k++) o2[k] *= alv;
            }
            const float p = exp2f(e - m);
            l += p;
            const v2f pv = (v2f){p, p};
            o2[0] += pv * t0.xy; o2[1] += pv * t0.zw;
            o2[2] += pv * t1.xy; o2[3] += pv * t1.zw;
            o2[4] += pv * t2.xy; o2[5] += pv * t2.zw;
            o2[6] += pv * t3.xy; o2[7] += pv * t3.zw;
        }
        __syncthreads();
    }

    float* Pp = P + (size_t)part * M_;
    #pragma unroll
    for (int q = 0; q < 4; q++) {
        v4f w;
        w.xy = o2[2*q]; w.zw = o2[2*q+1];
        *(v4f*)(Pp + rowbase + q * 4) = w;
    }
    if (dh == 0) {
        mb[part * ROWS_ + row] = m;
        lb[part * ROWS_ + row] = l;
    }
}

// merge JS partial (o,m,l) -> normalized attention output
template <int JS>
__global__ __launch_bounds__(256) void k_combine(
    const float* __restrict__ P, const float* __restrict__ mb,
    const float* __restrict__ lb, float* __restrict__ ao)
{
    const int idx = blockIdx.x * 256 + threadIdx.x;  // [0, ROWS_*D_)
    const int row = idx >> 5;
    float mv[JS], lv[JS];
    #pragma unroll
    for (int s = 0; s < JS; s++) { mv[s] = mb[s * ROWS_ + row]; lv[s] = lb[s * ROWS_ + row]; }
    float M = mv[0];
    #pragma unroll
    for (int s = 1; s < JS; s++) M = fmaxf(M, mv[s]);
    float w[JS], L = 0.f;
    #pragma unroll
    for (int s = 0; s < JS; s++) { w[s] = exp2f(mv[s] - M); L += w[s] * lv[s]; }
    const float inv = 1.f / L;
    float acc = 0.f;
    #pragma unroll
    for (int s = 0; s < JS; s++) acc += w[s] * P[(size_t)s * M_ + idx];
    ao[idx] = acc * inv;
}

// bias add + LayerNorm(128) (+optional ReLU); input [B,H,N,32] -> [B,N,128]
__global__ __launch_bounds__(64) void k_ln(
    const float* __restrict__ ain, const float* __restrict__ bias,
    const float* __restrict__ g, const float* __restrict__ bta,
    float* __restrict__ outp, int do_relu)
{
    const int row = blockIdx.x;
    const int b = row >> 11, n = row & (N_ - 1);
    const int t = threadIdx.x;
    const int c0 = t, c1 = t + 64;
    const size_t i0 = (((size_t)(b * H_ + (c0 >> 5))) * N_ + n) * D_ + (c0 & 31);
    const size_t i1 = (((size_t)(b * H_ + (c1 >> 5))) * N_ + n) * D_ + (c1 & 31);
    const float x0 = ain[i0] + bias[c0];
    const float x1 = ain[i1] + bias[c1];
    float s = x0 + x1;
    #pragma unroll
    for (int w = 1; w < 64; w <<= 1) s += __shfl_xor(s, w);
    const float mu = s * (1.f / 128.f);
    const float d0 = x0 - mu, d1 = x1 - mu;
    float q = d0 * d0 + d1 * d1;
    #pragma unroll
    for (int w = 1; w < 64; w <<= 1) q += __shfl_xor(q, w);
    const float rstd = rsqrtf(q * (1.f / 128.f) + 1e-5f);
    float y0 = d0 * rstd * g[c0] + bta[c0];
    float y1 = d1 * rstd * g[c1] + bta[c1];
    if (do_relu) { y0 = fmaxf(y0, 0.f); y1 = fmaxf(y1, 0.f); }
    outp[(size_t)row * HD_ + c0] = y0;
    outp[(size_t)row * HD_ + c1] = y1;
}

extern "C" void kernel_launch(void* const* d_in, const int* in_sizes, int n_in,
                              void* d_out, int out_size, void* d_ws, size_t ws_size,
                              hipStream_t stream) {
    const float* x    = (const float*)d_in[0];
    const float* Wl1  = (const float*)d_in[2];
    const float* bl1  = (const float*)d_in[3];
    const float* Wr1  = (const float*)d_in[4];
    const float* br1  = (const float*)d_in[5];
    const float* att1 = (const float*)d_in[6];
    const float* bias1= (const float*)d_in[7];
    const float* ln1g = (const float*)d_in[8];
    const float* ln1b = (const float*)d_in[9];
    const float* Wl2  = (const float*)d_in[10];
    const float* bl2  = (const float*)d_in[11];
    const float* Wr2  = (const float*)d_in[12];
    const float* br2  = (const float*)d_in[13];
    const float* att2 = (const float*)d_in[14];
    const float* bias2= (const float*)d_in[15];
    const float* ln2g = (const float*)d_in[16];
    const float* ln2b = (const float*)d_in[17];

    float* ws = (float*)d_ws;
    float* xl = ws;                       // M_  (also reused as combine output "ao")
    float* xr = xl + M_;                  // M_
    float* u  = xr + M_;                  // ROWS_

    // j-split factor: 4 if workspace allows, else 1
    const size_t need4 = (2 * M_ + ROWS_ + 4 * M_ + 8 * (size_t)ROWS_) * sizeof(float);
    const int js = (ws_size >= need4) ? 4 : 1;
    const int jlen = N_ / js;

    float* P  = u + ROWS_;                // js * M_
    float* mb = P + (size_t)js * M_;      // js * ROWS_
    float* lb = mb + (size_t)js * ROWS_;  // js * ROWS_
    float* h  = (js == 4) ? (P + M_) : (lb + (size_t)js * ROWS_);  // M_ (aliases P1 when js=4)
    float* ao = xl;                       // combine output aliases xl (dead after attn)
    float* outf = (float*)d_out;

    const int BN = B_ * N_;               // 8192
    // ---- layer 1 ----
    k_linear<<<BN / 32, 256, 0, stream>>>(x, Wl1, bl1, Wr1, br1, xl, xr, 32);
    k_u<<<ROWS_ / 256, 256, 0, stream>>>(xl, att1, u);
    k_attn<<<512 * js, 128, 0, stream>>>(xl, xr, u, att1, P, mb, lb, jlen);
    if (js == 4) k_combine<4><<<(ROWS_ * D_) / 256, 256, 0, stream>>>(P, mb, lb, ao);
    else         k_combine<1><<<(ROWS_ * D_) / 256, 256, 0, stream>>>(P, mb, lb, ao);
    k_ln<<<BN, 64, 0, stream>>>(ao, bias1, ln1g, ln1b, h, 1);
    // ---- layer 2 ----
    k_linear<<<BN / 32, 256, 0, stream>>>(h, Wl2, bl2, Wr2, br2, xl, xr, 128);
    k_u<<<ROWS_ / 256, 256, 0, stream>>>(xl, att2, u);
    k_attn<<<512 * js, 128, 0, stream>>>(xl, xr, u, att2, P, mb, lb, jlen);
    if (js == 4) k_combine<4><<<(ROWS_ * D_) / 256, 256, 0, stream>>>(P, mb, lb, ao);
    else         k_combine<1><<<(ROWS_ * D_) / 256, 256, 0, stream>>>(P, mb, lb, ao);
    k_ln<<<BN, 64, 0, stream>>>(ao, bias2, ln2g, ln2b, outf, 0);
}

// Round 5
// 451.749 us; speedup vs baseline: 13.2065x; 1.4024x over previous
//
#include <hip/hip_runtime.h>
#include <math.h>

#define LOG2E 1.4426950408889634f

constexpr int B_ = 4, N_ = 2048, H_ = 4, D_ = 32, HD_ = 128;
constexpr int BH_ = B_ * H_;          // 16
constexpr int ROWS_ = BH_ * N_;       // 32768
constexpr size_t M_ = (size_t)ROWS_ * D_;  // 1,048,576 floats

typedef float v2f __attribute__((ext_vector_type(2)));
typedef float v4f __attribute__((ext_vector_type(4)));
typedef _Float16 h2 __attribute__((ext_vector_type(2)));

// guaranteed packed f32 fma: o = a*b + o
static __device__ __forceinline__ void pkfma(v2f& o, v2f a, v2f b) {
    asm("v_pk_fma_f32 %0, %1, %2, %0" : "+v"(o) : "v"(a), "v"(b));
}
static __device__ __forceinline__ h2 habs2(h2 z) {
    unsigned int t = __builtin_bit_cast(unsigned int, z) & 0x7FFF7FFFu;
    return __builtin_bit_cast(h2, t);
}
static __device__ __forceinline__ h2 hadd2(unsigned int a, unsigned int b) {
    return __builtin_bit_cast(h2, a) + __builtin_bit_cast(h2, b);  // v_pk_add_f16
}

// x[BN,K] @ Wl/Wr[K,128] + bl/br -> xl (f32, [bh][n][d]) + xlh/xrh (f16 packed)
__global__ __launch_bounds__(256) void k_linear(
    const float* __restrict__ x,
    const float* __restrict__ Wl, const float* __restrict__ bl,
    const float* __restrict__ Wr, const float* __restrict__ br,
    float* __restrict__ xl, unsigned short* __restrict__ xlh,
    unsigned short* __restrict__ xrh, int K)
{
    __shared__ __align__(16) float xs[32 * 128];
    const int tid = threadIdx.x;
    const int r0 = blockIdx.x * 32;
    const float4* src = (const float4*)(x + (size_t)r0 * K);
    float4* dst = (float4*)xs;
    for (int idx = tid; idx < 8 * K; idx += 256) dst[idx] = src[idx];
    __syncthreads();

    const int c  = tid & 127;
    const int rg = tid >> 7;
    float accl[16], accr[16];
    const float blv = bl[c], brv = br[c];
    #pragma unroll
    for (int r = 0; r < 16; r++) { accl[r] = blv; accr[r] = brv; }
    #pragma unroll 8
    for (int k = 0; k < K; k++) {
        const float wl = Wl[k * HD_ + c];
        const float wr = Wr[k * HD_ + c];
        #pragma unroll
        for (int r = 0; r < 16; r++) {
            const float xv = xs[(rg * 16 + r) * K + k];
            accl[r] = fmaf(xv, wl, accl[r]);
            accr[r] = fmaf(xv, wr, accr[r]);
        }
    }
    const int h = c >> 5, d = c & 31;
    #pragma unroll
    for (int r = 0; r < 16; r++) {
        const int row = r0 + rg * 16 + r;
        const int b = row >> 11, n = row & (N_ - 1);
        const size_t o = (((size_t)(b * H_ + h)) * N_ + n) * D_ + d;
        xl[o] = accl[r];
        xlh[o] = __builtin_bit_cast(unsigned short, (_Float16)accl[r]);
        xrh[o] = __builtin_bit_cast(unsigned short, (_Float16)accr[r]);
    }
}

// u_j = 0.6*log2e * att_h . xl_j  (target-side term cancels in softmax)
__global__ __launch_bounds__(256) void k_u(
    const float* __restrict__ xl, const float* __restrict__ att,
    float* __restrict__ u)
{
    const int idx = blockIdx.x * 256 + threadIdx.x; // [0, ROWS_)
    const int h = (idx / N_) & (H_ - 1);
    const float4* a4 = (const float4*)(att + h * D_);
    const float4* l4 = (const float4*)(xl + (size_t)idx * D_);
    float su = 0.f;
    #pragma unroll
    for (int q = 0; q < 8; q++) {
        const float4 a = a4[q], lv = l4[q];
        su += a.x * lv.x + a.y * lv.y + a.z * lv.z + a.w * lv.w;
    }
    u[idx] = 0.6f * LOG2E * su;
}

// Flash GATv2 attention, lane-owns-row (64 rows/wave, no cross-lane ops).
// Score in packed f16 (pk_add_f16 + and + v_dot2_f32_f16), PV in packed f32
// (inline-asm v_pk_fma_f32). xl tiles staged in LDS, read as uniform
// broadcasts (conflict-free). j-split across `part`; unnormalized (o,m,l).
__global__ __launch_bounds__(256) void k_attn(
    const float* __restrict__ xl, const unsigned int* __restrict__ xlh,
    const unsigned int* __restrict__ xrh,
    const float* __restrict__ u, const float* __restrict__ att,
    float* __restrict__ P, float* __restrict__ mb, float* __restrict__ lb,
    int jlen)
{
    __shared__ __align__(16) float xs[64 * D_];          // f32 tile (PV)
    __shared__ __align__(16) unsigned int xh[64 * 16];   // f16 tile (score)
    __shared__ float us[64];
    const int tid = threadIdx.x, lane = tid & 63, wid = tid >> 6;
    const int blk = blockIdx.x & 127, part = blockIdx.x >> 7;
    const int bh = blk >> 3;
    const int i  = (blk & 7) * 256 + wid * 64 + lane;
    const int h  = bh & (H_ - 1);
    const int row = bh * N_ + i;

    h2 tc[16];
    {
        const float* ah = att + h * D_;
        #pragma unroll
        for (int q = 0; q < 16; q++) {
            h2 t;
            t.x = (_Float16)(ah[2 * q]     * (0.4f * LOG2E));
            t.y = (_Float16)(ah[2 * q + 1] * (0.4f * LOG2E));
            tc[q] = t;
        }
    }
    unsigned int xrp[16];
    {
        const uint4* s = (const uint4*)(xrh + (size_t)row * 16);
        const uint4 a = s[0], b = s[1], c = s[2], d = s[3];
        xrp[0]=a.x; xrp[1]=a.y; xrp[2]=a.z; xrp[3]=a.w;
        xrp[4]=b.x; xrp[5]=b.y; xrp[6]=b.z; xrp[7]=b.w;
        xrp[8]=c.x; xrp[9]=c.y; xrp[10]=c.z; xrp[11]=c.w;
        xrp[12]=d.x; xrp[13]=d.y; xrp[14]=d.z; xrp[15]=d.w;
    }

    float m = -INFINITY, l = 0.f;
    v2f o2[16];
    #pragma unroll
    for (int k = 0; k < 16; k++) o2[k] = (v2f){0.f, 0.f};

    const int jbeg = part * jlen, jend = jbeg + jlen;
    for (int j0 = jbeg; j0 < jend; j0 += 64) {
        const float4* s4 = (const float4*)(xl + ((size_t)bh * N_ + j0) * D_);
        ((float4*)xs)[tid] = s4[tid];
        ((float4*)xs)[tid + 256] = s4[tid + 256];
        const uint4* h4 = (const uint4*)(xlh + ((size_t)bh * N_ + j0) * 16);
        ((uint4*)xh)[tid] = h4[tid];
        if (tid < 64) us[tid] = u[bh * N_ + j0 + tid];
        __syncthreads();

        #pragma unroll 2
        for (int q = 0; q < 64; q++) {
            const uint4* hq = (const uint4*)(xh + q * 16);
            const uint4 w0 = hq[0], w1 = hq[1], w2 = hq[2], w3 = hq[3];
            float a0 = us[q], a1 = 0.f, a2 = 0.f, a3 = 0.f;
            a0 = __builtin_amdgcn_fdot2(habs2(hadd2(w0.x, xrp[0])),  tc[0],  a0, false);
            a1 = __builtin_amdgcn_fdot2(habs2(hadd2(w0.y, xrp[1])),  tc[1],  a1, false);
            a2 = __builtin_amdgcn_fdot2(habs2(hadd2(w0.z, xrp[2])),  tc[2],  a2, false);
            a3 = __builtin_amdgcn_fdot2(habs2(hadd2(w0.w, xrp[3])),  tc[3],  a3, false);
            a0 = __builtin_amdgcn_fdot2(habs2(hadd2(w1.x, xrp[4])),  tc[4],  a0, false);
            a1 = __builtin_amdgcn_fdot2(habs2(hadd2(w1.y, xrp[5])),  tc[5],  a1, false);
            a2 = __builtin_amdgcn_fdot2(habs2(hadd2(w1.z, xrp[6])),  tc[6],  a2, false);
            a3 = __builtin_amdgcn_fdot2(habs2(hadd2(w1.w, xrp[7])),  tc[7],  a3, false);
            a0 = __builtin_amdgcn_fdot2(habs2(hadd2(w2.x, xrp[8])),  tc[8],  a0, false);
            a1 = __builtin_amdgcn_fdot2(habs2(hadd2(w2.y, xrp[9])),  tc[9],  a1, false);
            a2 = __builtin_amdgcn_fdot2(habs2(hadd2(w2.z, xrp[10])), tc[10], a2, false);
            a3 = __builtin_amdgcn_fdot2(habs2(hadd2(w2.w, xrp[11])), tc[11], a3, false);
            a0 = __builtin_amdgcn_fdot2(habs2(hadd2(w3.x, xrp[12])), tc[12], a0, false);
            a1 = __builtin_amdgcn_fdot2(habs2(hadd2(w3.y, xrp[13])), tc[13], a1, false);
            a2 = __builtin_amdgcn_fdot2(habs2(hadd2(w3.z, xrp[14])), tc[14], a2, false);
            a3 = __builtin_amdgcn_fdot2(habs2(hadd2(w3.w, xrp[15])), tc[15], a3, false);
            const float e = (a0 + a1) + (a2 + a3);
            if (__builtin_expect(e > m, 0)) {       // rare after warmup
                const float al = exp2f(m - e);
                m = e;
                l *= al;
                const v2f alv = (v2f){al, al};
                #pragma unroll
                for (int k = 0; k < 16; k++) o2[k] *= alv;
            }
            const float p = exp2f(e - m);
            l += p;
            const v2f pp = (v2f){p, p};
            const v4f* rf = (const v4f*)(xs + q * D_);
            #pragma unroll
            for (int k = 0; k < 8; k++) {
                const v4f t = rf[k];
                pkfma(o2[2 * k],     pp, t.xy);
                pkfma(o2[2 * k + 1], pp, t.zw);
            }
        }
        __syncthreads();
    }

    float* Pp = P + (size_t)part * M_ + (size_t)row * D_;
    #pragma unroll
    for (int k = 0; k < 8; k++) {
        v4f w;
        w.xy = o2[2 * k]; w.zw = o2[2 * k + 1];
        ((v4f*)Pp)[k] = w;
    }
    mb[part * ROWS_ + row] = m;
    lb[part * ROWS_ + row] = l;
}

// merge JS partial (o,m,l) -> normalized attention output
template <int JS>
__global__ __launch_bounds__(256) void k_combine(
    const float* __restrict__ P, const float* __restrict__ mb,
    const float* __restrict__ lb, float* __restrict__ ao)
{
    const int idx = blockIdx.x * 256 + threadIdx.x;  // [0, ROWS_*D_)
    const int row = idx >> 5;
    float mv[JS], lv[JS];
    #pragma unroll
    for (int s = 0; s < JS; s++) { mv[s] = mb[s * ROWS_ + row]; lv[s] = lb[s * ROWS_ + row]; }
    float M = mv[0];
    #pragma unroll
    for (int s = 1; s < JS; s++) M = fmaxf(M, mv[s]);
    float w[JS], L = 0.f;
    #pragma unroll
    for (int s = 0; s < JS; s++) { w[s] = exp2f(mv[s] - M); L += w[s] * lv[s]; }
    const float inv = 1.f / L;
    float acc = 0.f;
    #pragma unroll
    for (int s = 0; s < JS; s++) acc += w[s] * P[(size_t)s * M_ + idx];
    ao[idx] = acc * inv;
}

// bias add + LayerNorm(128) (+optional ReLU); input [B,H,N,32] -> [B,N,128]
__global__ __launch_bounds__(64) void k_ln(
    const float* __restrict__ ain, const float* __restrict__ bias,
    const float* __restrict__ g, const float* __restrict__ bta,
    float* __restrict__ outp, int do_relu)
{
    const int row = blockIdx.x;
    const int b = row >> 11, n = row & (N_ - 1);
    const int t = threadIdx.x;
    const int c0 = t, c1 = t + 64;
    const size_t i0 = (((size_t)(b * H_ + (c0 >> 5))) * N_ + n) * D_ + (c0 & 31);
    const size_t i1 = (((size_t)(b * H_ + (c1 >> 5))) * N_ + n) * D_ + (c1 & 31);
    const float x0 = ain[i0] + bias[c0];
    const float x1 = ain[i1] + bias[c1];
    float s = x0 + x1;
    #pragma unroll
    for (int w = 1; w < 64; w <<= 1) s += __shfl_xor(s, w);
    const float mu = s * (1.f / 128.f);
    const float d0 = x0 - mu, d1 = x1 - mu;
    float q = d0 * d0 + d1 * d1;
    #pragma unroll
    for (int w = 1; w < 64; w <<= 1) q += __shfl_xor(q, w);
    const float rstd = rsqrtf(q * (1.f / 128.f) + 1e-5f);
    float y0 = d0 * rstd * g[c0] + bta[c0];
    float y1 = d1 * rstd * g[c1] + bta[c1];
    if (do_relu) { y0 = fmaxf(y0, 0.f); y1 = fmaxf(y1, 0.f); }
    outp[(size_t)row * HD_ + c0] = y0;
    outp[(size_t)row * HD_ + c1] = y1;
}

extern "C" void kernel_launch(void* const* d_in, const int* in_sizes, int n_in,
                              void* d_out, int out_size, void* d_ws, size_t ws_size,
                              hipStream_t stream) {
    const float* x    = (const float*)d_in[0];
    const float* Wl1  = (const float*)d_in[2];
    const float* bl1  = (const float*)d_in[3];
    const float* Wr1  = (const float*)d_in[4];
    const float* br1  = (const float*)d_in[5];
    const float* att1 = (const float*)d_in[6];
    const float* bias1= (const float*)d_in[7];
    const float* ln1g = (const float*)d_in[8];
    const float* ln1b = (const float*)d_in[9];
    const float* Wl2  = (const float*)d_in[10];
    const float* bl2  = (const float*)d_in[11];
    const float* Wr2  = (const float*)d_in[12];
    const float* br2  = (const float*)d_in[13];
    const float* att2 = (const float*)d_in[14];
    const float* bias2= (const float*)d_in[15];
    const float* ln2g = (const float*)d_in[16];
    const float* ln2b = (const float*)d_in[17];

    float* ws = (float*)d_ws;
    float* xl = ws;                                   // M_ f32 (also combine out)
    unsigned short* xlh = (unsigned short*)(xl + M_); // M_ halfs = M_/2 floats
    unsigned short* xrh = xlh + M_;                   // M_ halfs
    float* u  = xl + 2 * M_;                          // ROWS_

    // j-split: pick the largest that fits ws. bytes = (2M + ROWS + js*(M+2*ROWS))*4
    int js = 1;
    for (int cand = 8; cand >= 1; cand >>= 1) {
        const size_t need = (2 * M_ + ROWS_ + (size_t)cand * (M_ + 2 * (size_t)ROWS_)) * sizeof(float);
        if (ws_size >= need) { js = cand; break; }
    }
    const int jlen = N_ / js;

    float* P  = u + ROWS_;                 // js * M_
    float* mb = P + (size_t)js * M_;       // js * ROWS_
    float* lb = mb + (size_t)js * ROWS_;   // js * ROWS_
    float* h  = P;                         // aliases P slab 0 (P dead after combine)
    float* ao = xl;                        // combine output aliases xl
    float* outf = (float*)d_out;

    const int BN = B_ * N_;                // 8192
    // ---- layer 1 ----
    k_linear<<<BN / 32, 256, 0, stream>>>(x, Wl1, bl1, Wr1, br1, xl, xlh, xrh, 32);
    k_u<<<ROWS_ / 256, 256, 0, stream>>>(xl, att1, u);
    k_attn<<<128 * js, 256, 0, stream>>>(xl, (const unsigned int*)xlh, (const unsigned int*)xrh,
                                         u, att1, P, mb, lb, jlen);
    if      (js == 8) k_combine<8><<<(ROWS_ * D_) / 256, 256, 0, stream>>>(P, mb, lb, ao);
    else if (js == 4) k_combine<4><<<(ROWS_ * D_) / 256, 256, 0, stream>>>(P, mb, lb, ao);
    else if (js == 2) k_combine<2><<<(ROWS_ * D_) / 256, 256, 0, stream>>>(P, mb, lb, ao);
    else              k_combine<1><<<(ROWS_ * D_) / 256, 256, 0, stream>>>(P, mb, lb, ao);
    k_ln<<<BN, 64, 0, stream>>>(ao, bias1, ln1g, ln1b, h, 1);
    // ---- layer 2 ----
    k_linear<<<BN / 32, 256, 0, stream>>>(h, Wl2, bl2, Wr2, br2, xl, xlh, xrh, 128);
    k_u<<<ROWS_ / 256, 256, 0, stream>>>(xl, att2, u);
    k_attn<<<128 * js, 256, 0, stream>>>(xl, (const unsigned int*)xlh, (const unsigned int*)xrh,
                                         u, att2, P, mb, lb, jlen);
    if      (js == 8) k_combine<8><<<(ROWS_ * D_) / 256, 256, 0, stream>>>(P, mb, lb, ao);
    else if (js == 4) k_combine<4><<<(ROWS_ * D_) / 256, 256, 0, stream>>>(P, mb, lb, ao);
    else if (js == 2) k_combine<2><<<(ROWS_ * D_) / 256, 256, 0, stream>>>(P, mb, lb, ao);
    else              k_combine<1><<<(ROWS_ * D_) / 256, 256, 0, stream>>>(P, mb, lb, ao);
    k_ln<<<BN, 64, 0, stream>>>(ao, bias2, ln2g, ln2b, outf, 0);
}